// Round 10
// baseline (121.619 us; speedup 1.0000x reference)
//
#include <hip/hip_runtime.h>

// LQActiv forward: 2-bit quantization + least-squares basis refit.
// Output layout: [N floats wq][2 floats new_basis].
//
// Round 10: DOSE-RESPONSE A/B. Store-bearing kernels scale linearly with
// VALU/element (copy=33us, quant6=69, fused13=135 per 206MB) though
// VALUBusy is 7%. Split the quantize pass into 4 disjoint quarters, one
// variant each -> 4 per-dispatch rocprof timings in one round, output
// still correct:
//   qA: 6-inst select, NT load / NT store   (baseline)
//   qB: 6-inst select, NT load / cached store (store-policy A/B)
//   qC: 4-inst select (symmetric levels), NT/NT (VALU-dose A/B)
//   qD: 6-inst select, cached load / NT store (load-policy A/B)
// lq_stats / lq_final unchanged from round 8/9.

#define NBLOCKS 2048
#define NTHREADS 256

typedef float fvec4 __attribute__((ext_vector_type(4)));

// ---- K1: stats only (reduce shape) — unchanged ----
__global__ __launch_bounds__(NTHREADS) void lq_stats(
    const float* __restrict__ x, const float* __restrict__ basis,
    float* __restrict__ partials, int n4) {
  const float v0 = basis[0], v1 = basis[1];
  float lev[4] = {-v0 - v1, -v0 + v1, v0 - v1, v0 + v1};
#define CSWAP(i, j)                                          \
  if (lev[i] > lev[j]) { float t = lev[i]; lev[i] = lev[j]; lev[j] = t; }
  CSWAP(0, 1) CSWAP(2, 3) CSWAP(0, 2) CSWAP(1, 3) CSWAP(1, 2)
#undef CSWAP
  const float T0 = 0.5f * (lev[0] + lev[1]);
  const float T1 = 0.5f * (lev[1] + lev[2]);
  const float T2 = 0.5f * (lev[2] + lev[3]);

  int c0 = 0, c1 = 0, c2 = 0;
  float sw = 0.f, sw0 = 0.f, sw1 = 0.f, sw2 = 0.f;

  auto acc = [&](float w) {
    const bool t0 = w > T0;
    const bool t1 = w > T1;
    const bool t2 = w > T2;
    c0 += t0;
    c1 += t1;
    c2 += t2;
    sw += w;
    sw0 += t0 ? w : 0.f;
    sw1 += t1 ? w : 0.f;
    sw2 += t2 ? w : 0.f;
  };

  const fvec4* __restrict__ x4 = (const fvec4*)x;
  const int tid = blockIdx.x * blockDim.x + threadIdx.x;
  const int stride = gridDim.x * blockDim.x;
  for (int i = tid; i < n4; i += stride) {
    fvec4 w = __builtin_nontemporal_load(&x4[i]);
    acc(w.x);
    acc(w.y);
    acc(w.z);
    acc(w.w);
  }

  float f0 = (float)c0, f1 = (float)c1, f2 = (float)c2;
  for (int off = 32; off; off >>= 1) {
    f0 += __shfl_down(f0, off);
    f1 += __shfl_down(f1, off);
    f2 += __shfl_down(f2, off);
    sw += __shfl_down(sw, off);
    sw0 += __shfl_down(sw0, off);
    sw1 += __shfl_down(sw1, off);
    sw2 += __shfl_down(sw2, off);
  }
  __shared__ float red[7][NTHREADS / 64];
  const int lane = threadIdx.x & 63;
  const int wid = threadIdx.x >> 6;
  if (lane == 0) {
    red[0][wid] = f0;
    red[1][wid] = f1;
    red[2][wid] = f2;
    red[3][wid] = sw;
    red[4][wid] = sw0;
    red[5][wid] = sw1;
    red[6][wid] = sw2;
  }
  __syncthreads();
  if (threadIdx.x < 7) {
    float r = 0.f;
#pragma unroll
    for (int w = 0; w < NTHREADS / 64; ++w) r += red[threadIdx.x][w];
    partials[7 * blockIdx.x + threadIdx.x] = r;
  }
}

// ---- shared helpers for the quant variants ----
__device__ __forceinline__ void sorted_levels(const float* basis, float& Q0,
                                              float& Q1, float& Q2, float& Q3) {
  const float v0 = basis[0], v1 = basis[1];
  float lev[4] = {-v0 - v1, -v0 + v1, v0 - v1, v0 + v1};
#define CSWAP(i, j)                                          \
  if (lev[i] > lev[j]) { float t = lev[i]; lev[i] = lev[j]; lev[j] = t; }
  CSWAP(0, 1) CSWAP(2, 3) CSWAP(0, 2) CSWAP(1, 3) CSWAP(1, 2)
#undef CSWAP
  Q0 = lev[0];
  Q1 = lev[1];
  Q2 = lev[2];
  Q3 = lev[3];
}

// ---- qA: 6-inst select, NT load / NT store ----
__global__ __launch_bounds__(NTHREADS) void lq_qA_nt_nt6(
    const float* __restrict__ x, const float* __restrict__ basis,
    float* __restrict__ out, int lo4, int hi4) {
  float Q0, Q1, Q2, Q3;
  sorted_levels(basis, Q0, Q1, Q2, Q3);
  const float T0 = 0.5f * (Q0 + Q1);
  const float T1 = 0.5f * (Q1 + Q2);
  const float T2 = 0.5f * (Q2 + Q3);
  auto quant = [&](float w) -> float {
    float q = (w > T0) ? Q1 : Q0;
    q = (w > T1) ? Q2 : q;
    q = (w > T2) ? Q3 : q;
    return q;
  };
  const fvec4* __restrict__ x4 = (const fvec4*)x;
  fvec4* __restrict__ o4 = (fvec4*)out;
  const int tid = blockIdx.x * blockDim.x + threadIdx.x;
  const int stride = gridDim.x * blockDim.x;
  for (int i = lo4 + tid; i < hi4; i += stride) {
    fvec4 w = __builtin_nontemporal_load(&x4[i]);
    fvec4 q;
    q.x = quant(w.x);
    q.y = quant(w.y);
    q.z = quant(w.z);
    q.w = quant(w.w);
    __builtin_nontemporal_store(q, &o4[i]);
  }
}

// ---- qB: 6-inst select, NT load / CACHED store ----
__global__ __launch_bounds__(NTHREADS) void lq_qB_nt_c6(
    const float* __restrict__ x, const float* __restrict__ basis,
    float* __restrict__ out, int lo4, int hi4) {
  float Q0, Q1, Q2, Q3;
  sorted_levels(basis, Q0, Q1, Q2, Q3);
  const float T0 = 0.5f * (Q0 + Q1);
  const float T1 = 0.5f * (Q1 + Q2);
  const float T2 = 0.5f * (Q2 + Q3);
  auto quant = [&](float w) -> float {
    float q = (w > T0) ? Q1 : Q0;
    q = (w > T1) ? Q2 : q;
    q = (w > T2) ? Q3 : q;
    return q;
  };
  const fvec4* __restrict__ x4 = (const fvec4*)x;
  fvec4* __restrict__ o4 = (fvec4*)out;
  const int tid = blockIdx.x * blockDim.x + threadIdx.x;
  const int stride = gridDim.x * blockDim.x;
  for (int i = lo4 + tid; i < hi4; i += stride) {
    fvec4 w = __builtin_nontemporal_load(&x4[i]);
    fvec4 q;
    q.x = quant(w.x);
    q.y = quant(w.y);
    q.z = quant(w.z);
    q.w = quant(w.w);
    o4[i] = q;
  }
}

// ---- qC: 4-inst symmetric select, NT / NT ----
// Levels are always {+-(v0+v1), +-(v0-v1)} -> symmetric. T1=0, T2=vm.
// Exact boundary semantics: big = (w > vm) || (w <= -vm); mag = big?hi:lo;
// q = copysign(mag, w). (w==+0.0 edge has measure ~0 in normal data.)
__global__ __launch_bounds__(NTHREADS) void lq_qC_nt_nt4(
    const float* __restrict__ x, const float* __restrict__ basis,
    float* __restrict__ out, int lo4, int hi4) {
  float Q0, Q1, Q2, Q3;
  sorted_levels(basis, Q0, Q1, Q2, Q3);
  const float hi = Q3;                 // +(|v0|+|v1|)
  const float lo = Q2;                 // +||v0|-|v1||
  const float vm = 0.5f * (Q2 + Q3);   // T2
  const float nvm = -vm;
  auto quant = [&](float w) -> float {
    const bool big = (w > vm) | (w <= nvm);
    const float mag = big ? hi : lo;
    return __builtin_copysignf(mag, w);
  };
  const fvec4* __restrict__ x4 = (const fvec4*)x;
  fvec4* __restrict__ o4 = (fvec4*)out;
  const int tid = blockIdx.x * blockDim.x + threadIdx.x;
  const int stride = gridDim.x * blockDim.x;
  for (int i = lo4 + tid; i < hi4; i += stride) {
    fvec4 w = __builtin_nontemporal_load(&x4[i]);
    fvec4 q;
    q.x = quant(w.x);
    q.y = quant(w.y);
    q.z = quant(w.z);
    q.w = quant(w.w);
    __builtin_nontemporal_store(q, &o4[i]);
  }
}

// ---- qD: 6-inst select, CACHED load / NT store (handles scalar tail) ----
__global__ __launch_bounds__(NTHREADS) void lq_qD_c_nt6(
    const float* __restrict__ x, const float* __restrict__ basis,
    float* __restrict__ out, int lo4, int hi4, int n) {
  float Q0, Q1, Q2, Q3;
  sorted_levels(basis, Q0, Q1, Q2, Q3);
  const float T0 = 0.5f * (Q0 + Q1);
  const float T1 = 0.5f * (Q1 + Q2);
  const float T2 = 0.5f * (Q2 + Q3);
  auto quant = [&](float w) -> float {
    float q = (w > T0) ? Q1 : Q0;
    q = (w > T1) ? Q2 : q;
    q = (w > T2) ? Q3 : q;
    return q;
  };
  const fvec4* __restrict__ x4 = (const fvec4*)x;
  fvec4* __restrict__ o4 = (fvec4*)out;
  const int tid = blockIdx.x * blockDim.x + threadIdx.x;
  const int stride = gridDim.x * blockDim.x;
  for (int i = lo4 + tid; i < hi4; i += stride) {
    fvec4 w = x4[i];
    fvec4 q;
    q.x = quant(w.x);
    q.y = quant(w.y);
    q.z = quant(w.z);
    q.w = quant(w.w);
    __builtin_nontemporal_store(q, &o4[i]);
  }
  for (int k = hi4 * 4 + tid; k < n; k += stride) {
    out[k] = quant(x[k]);
  }
}

// ---- K3: final reduce + 2x2 solve — unchanged ----
__global__ __launch_bounds__(NTHREADS) void lq_final(
    const float* __restrict__ partials, const float* __restrict__ basis,
    float* __restrict__ out_basis, int n, int nparts) {
  double C0 = 0, C1 = 0, C2 = 0, SW = 0, SW0 = 0, SW1 = 0, SW2 = 0;
  for (int i = threadIdx.x; i < nparts; i += blockDim.x) {
    C0 += (double)partials[7 * i + 0];
    C1 += (double)partials[7 * i + 1];
    C2 += (double)partials[7 * i + 2];
    SW += (double)partials[7 * i + 3];
    SW0 += (double)partials[7 * i + 4];
    SW1 += (double)partials[7 * i + 5];
    SW2 += (double)partials[7 * i + 6];
  }
  for (int off = 32; off; off >>= 1) {
    C0 += __shfl_down(C0, off);
    C1 += __shfl_down(C1, off);
    C2 += __shfl_down(C2, off);
    SW += __shfl_down(SW, off);
    SW0 += __shfl_down(SW0, off);
    SW1 += __shfl_down(SW1, off);
    SW2 += __shfl_down(SW2, off);
  }
  __shared__ double red[7][NTHREADS / 64];
  const int lane = threadIdx.x & 63;
  const int wid = threadIdx.x >> 6;
  if (lane == 0) {
    red[0][wid] = C0;
    red[1][wid] = C1;
    red[2][wid] = C2;
    red[3][wid] = SW;
    red[4][wid] = SW0;
    red[5][wid] = SW1;
    red[6][wid] = SW2;
  }
  __syncthreads();
  if (threadIdx.x == 0) {
    double c0 = 0, c1 = 0, c2 = 0, s = 0, s0 = 0, s1 = 0, s2 = 0;
#pragma unroll
    for (int w = 0; w < NTHREADS / 64; ++w) {
      c0 += red[0][w];
      c1 += red[1][w];
      c2 += red[2][w];
      s += red[3][w];
      s0 += red[4][w];
      s1 += red[5][w];
      s2 += red[6][w];
    }
    const float v0 = basis[0], v1 = basis[1];
    float lev[4] = {-v0 - v1, -v0 + v1, v0 - v1, v0 + v1};
    float e0[4] = {-1.f, -1.f, 1.f, 1.f};
    float e1[4] = {-1.f, 1.f, -1.f, 1.f};
#define CSWAP(i, j)                                                   \
    if (lev[i] > lev[j]) {                                            \
      float t = lev[i]; lev[i] = lev[j]; lev[j] = t;                  \
      t = e0[i]; e0[i] = e0[j]; e0[j] = t;                            \
      t = e1[i]; e1[i] = e1[j]; e1[j] = t;                            \
    }
    CSWAP(0, 1) CSWAP(2, 3) CSWAP(0, 2) CSWAP(1, 3) CSWAP(1, 2)
#undef CSWAP
    const double A0 = e0[0], A1 = e0[1], A2 = e0[2], A3 = e0[3];
    const double B0 = e1[0], B1 = e1[1], B2 = e1[2], B3 = e1[3];
    const double N = (double)n;
    const double Sb0 = A0 * s + (A1 - A0) * s0 + (A2 - A1) * s1 + (A3 - A2) * s2;
    const double Sb1 = B0 * s + (B1 - B0) * s0 + (B2 - B1) * s1 + (B3 - B2) * s2;
    const double P0 = A0 * B0, P1 = A1 * B1, P2 = A2 * B2, P3 = A3 * B3;
    const double S01 = P0 * N + (P1 - P0) * c0 + (P2 - P1) * c1 + (P3 - P2) * c2;
    const double det = N * N - S01 * S01;
    const double nv0 = (N * Sb0 - S01 * Sb1) / det;
    const double nv1 = (N * Sb1 - S01 * Sb0) / det;
    out_basis[0] = (float)(0.9 * (double)v0 + 0.1 * nv0);
    out_basis[1] = (float)(0.9 * (double)v1 + 0.1 * nv1);
  }
}

extern "C" void kernel_launch(void* const* d_in, const int* in_sizes, int n_in,
                              void* d_out, int out_size, void* d_ws, size_t ws_size,
                              hipStream_t stream) {
  const float* x = (const float*)d_in[0];
  const float* basis = (const float*)d_in[1];
  float* out = (float*)d_out;
  const int n = in_sizes[0];
  float* partials = (float*)d_ws;  // nblocks * 7 floats

  int nblocks = NBLOCKS;
  const int maxb = (int)(ws_size / (7 * sizeof(float)));
  if (nblocks > maxb) nblocks = maxb;
  if (nblocks < 1) nblocks = 1;

  const int n4 = n / 4;
  const int q = n4 / 4;  // quarter (in vec4 units)

  lq_stats<<<nblocks, NTHREADS, 0, stream>>>(x, basis, partials, n4);
  lq_qA_nt_nt6<<<NBLOCKS, NTHREADS, 0, stream>>>(x, basis, out, 0 * q, 1 * q);
  lq_qB_nt_c6<<<NBLOCKS, NTHREADS, 0, stream>>>(x, basis, out, 1 * q, 2 * q);
  lq_qC_nt_nt4<<<NBLOCKS, NTHREADS, 0, stream>>>(x, basis, out, 2 * q, 3 * q);
  lq_qD_c_nt6<<<NBLOCKS, NTHREADS, 0, stream>>>(x, basis, out, 3 * q, n4, n);
  lq_final<<<1, NTHREADS, 0, stream>>>(partials, basis, out + n, n, nblocks);
}

// Round 11
// 94.340 us; speedup vs baseline: 1.2892x; 1.2892x over previous
//
#include <hip/hip_runtime.h>

// LQActiv forward: 2-bit quantization + least-squares basis refit.
// Output layout: [N floats wq][2 floats new_basis].
//
// Round 11: software-pipeline lq_quant. Theory: vmcnt counts loads AND
// stores; in the straight-line loop the wait before using iteration j's
// data also drains iteration j-1's store-acks (NT store ack ~ HBM round
// trip), serializing the wave on store latency. Copy escapes (compiler
// hoists next loads above stores when no VALU web intervenes); quant
// doesn't. Fix: explicit double-buffered register pipeline — issue
// loads(j+1) BEFORE compute/store(j), so loads are always the oldest
// outstanding vmem ops and the load-use wait never drains stores.
//
//   K1 lq_stats: reduce-shaped, NT reads, 7 partials/block (unchanged).
//   K2 lq_quant: pipelined 4-deep NT copy-shape + 6-inst select.
//   K3 lq_final: f64 reduce + telescoped encoding algebra + 2x2 solve.

#define NBLOCKS 2048
#define NTHREADS 256
#define QVEC 4  // fvec4 per thread per lq_quant stage

typedef float fvec4 __attribute__((ext_vector_type(4)));

// ---- K1: stats only (reduce shape) — unchanged ----
__global__ __launch_bounds__(NTHREADS) void lq_stats(
    const float* __restrict__ x, const float* __restrict__ basis,
    float* __restrict__ partials, int n4) {
  const float v0 = basis[0], v1 = basis[1];
  float lev[4] = {-v0 - v1, -v0 + v1, v0 - v1, v0 + v1};
#define CSWAP(i, j)                                          \
  if (lev[i] > lev[j]) { float t = lev[i]; lev[i] = lev[j]; lev[j] = t; }
  CSWAP(0, 1) CSWAP(2, 3) CSWAP(0, 2) CSWAP(1, 3) CSWAP(1, 2)
#undef CSWAP
  const float T0 = 0.5f * (lev[0] + lev[1]);
  const float T1 = 0.5f * (lev[1] + lev[2]);
  const float T2 = 0.5f * (lev[2] + lev[3]);

  int c0 = 0, c1 = 0, c2 = 0;
  float sw = 0.f, sw0 = 0.f, sw1 = 0.f, sw2 = 0.f;

  auto acc = [&](float w) {
    const bool t0 = w > T0;
    const bool t1 = w > T1;
    const bool t2 = w > T2;
    c0 += t0;
    c1 += t1;
    c2 += t2;
    sw += w;
    sw0 += t0 ? w : 0.f;
    sw1 += t1 ? w : 0.f;
    sw2 += t2 ? w : 0.f;
  };

  const fvec4* __restrict__ x4 = (const fvec4*)x;
  const int tid = blockIdx.x * blockDim.x + threadIdx.x;
  const int stride = gridDim.x * blockDim.x;
  for (int i = tid; i < n4; i += stride) {
    fvec4 w = __builtin_nontemporal_load(&x4[i]);
    acc(w.x);
    acc(w.y);
    acc(w.z);
    acc(w.w);
  }

  float f0 = (float)c0, f1 = (float)c1, f2 = (float)c2;
  for (int off = 32; off; off >>= 1) {
    f0 += __shfl_down(f0, off);
    f1 += __shfl_down(f1, off);
    f2 += __shfl_down(f2, off);
    sw += __shfl_down(sw, off);
    sw0 += __shfl_down(sw0, off);
    sw1 += __shfl_down(sw1, off);
    sw2 += __shfl_down(sw2, off);
  }
  __shared__ float red[7][NTHREADS / 64];
  const int lane = threadIdx.x & 63;
  const int wid = threadIdx.x >> 6;
  if (lane == 0) {
    red[0][wid] = f0;
    red[1][wid] = f1;
    red[2][wid] = f2;
    red[3][wid] = sw;
    red[4][wid] = sw0;
    red[5][wid] = sw1;
    red[6][wid] = sw2;
  }
  __syncthreads();
  if (threadIdx.x < 7) {
    float r = 0.f;
#pragma unroll
    for (int w = 0; w < NTHREADS / 64; ++w) r += red[threadIdx.x][w];
    partials[7 * blockIdx.x + threadIdx.x] = r;
  }
}

// ---- K2: quantize, software-pipelined double-buffered registers ----
__global__ __launch_bounds__(NTHREADS) void lq_quant(
    const float* __restrict__ x, const float* __restrict__ basis,
    float* __restrict__ out, int n, int n4) {
  const float v0 = basis[0], v1 = basis[1];
  float lev[4] = {-v0 - v1, -v0 + v1, v0 - v1, v0 + v1};
#define CSWAP(i, j)                                          \
  if (lev[i] > lev[j]) { float t = lev[i]; lev[i] = lev[j]; lev[j] = t; }
  CSWAP(0, 1) CSWAP(2, 3) CSWAP(0, 2) CSWAP(1, 3) CSWAP(1, 2)
#undef CSWAP
  const float Q0 = lev[0], Q1 = lev[1], Q2 = lev[2], Q3 = lev[3];
  const float T0 = 0.5f * (Q0 + Q1);
  const float T1 = 0.5f * (Q1 + Q2);
  const float T2 = 0.5f * (Q2 + Q3);

  auto quant = [&](float w) -> float {
    float q = (w > T0) ? Q1 : Q0;  // thresholds monotone:
    q = (w > T1) ? Q2 : q;         // q = Qlevels[(w>T0)+(w>T1)+(w>T2)]
    q = (w > T2) ? Q3 : q;
    return q;
  };
  auto quant4 = [&](fvec4 w) -> fvec4 {
    fvec4 q;
    q.x = quant(w.x);
    q.y = quant(w.y);
    q.z = quant(w.z);
    q.w = quant(w.w);
    return q;
  };

  const fvec4* __restrict__ x4 = (const fvec4*)x;
  fvec4* __restrict__ o4 = (fvec4*)out;

  const int grid_tile = NBLOCKS * NTHREADS * QVEC;
  const int nfull = n4 / grid_tile;
  const int rem_start = nfull * grid_tile;
  const int tbase = blockIdx.x * (NTHREADS * QVEC) + threadIdx.x;

  fvec4 a0, a1, a2, a3;  // buffer A
  fvec4 b0, b1, b2, b3;  // buffer B

  auto LOAD = [&](int j, fvec4& r0, fvec4& r1, fvec4& r2, fvec4& r3) {
    const int base = j * grid_tile + tbase;
    r0 = __builtin_nontemporal_load(&x4[base + 0 * NTHREADS]);
    r1 = __builtin_nontemporal_load(&x4[base + 1 * NTHREADS]);
    r2 = __builtin_nontemporal_load(&x4[base + 2 * NTHREADS]);
    r3 = __builtin_nontemporal_load(&x4[base + 3 * NTHREADS]);
  };
  auto STORE = [&](int j, fvec4& r0, fvec4& r1, fvec4& r2, fvec4& r3) {
    const int base = j * grid_tile + tbase;
    __builtin_nontemporal_store(quant4(r0), &o4[base + 0 * NTHREADS]);
    __builtin_nontemporal_store(quant4(r1), &o4[base + 1 * NTHREADS]);
    __builtin_nontemporal_store(quant4(r2), &o4[base + 2 * NTHREADS]);
    __builtin_nontemporal_store(quant4(r3), &o4[base + 3 * NTHREADS]);
  };

  // pipeline: loads(j+1) issue before compute/store(j)
  int j = 0;
  if (nfull > 0) LOAD(0, a0, a1, a2, a3);
  for (; j + 2 <= nfull; j += 2) {
    LOAD(j + 1, b0, b1, b2, b3);
    STORE(j, a0, a1, a2, a3);
    if (j + 2 < nfull) LOAD(j + 2, a0, a1, a2, a3);
    STORE(j + 1, b0, b1, b2, b3);
  }
  if (j < nfull) STORE(j, a0, a1, a2, a3);

  // vec4 remainder (1-deep grid-stride)
  for (int i = rem_start + blockIdx.x * NTHREADS + threadIdx.x; i < n4;
       i += NBLOCKS * NTHREADS) {
    fvec4 w = __builtin_nontemporal_load(&x4[i]);
    __builtin_nontemporal_store(quant4(w), &o4[i]);
  }
  // scalar tail (N divisible by 4; kept for safety)
  for (int k = n4 * 4 + blockIdx.x * NTHREADS + threadIdx.x; k < n;
       k += NBLOCKS * NTHREADS) {
    out[k] = quant(x[k]);
  }
}

// ---- K3: final reduce + 2x2 solve — unchanged ----
__global__ __launch_bounds__(NTHREADS) void lq_final(
    const float* __restrict__ partials, const float* __restrict__ basis,
    float* __restrict__ out_basis, int n, int nparts) {
  double C0 = 0, C1 = 0, C2 = 0, SW = 0, SW0 = 0, SW1 = 0, SW2 = 0;
  for (int i = threadIdx.x; i < nparts; i += blockDim.x) {
    C0 += (double)partials[7 * i + 0];
    C1 += (double)partials[7 * i + 1];
    C2 += (double)partials[7 * i + 2];
    SW += (double)partials[7 * i + 3];
    SW0 += (double)partials[7 * i + 4];
    SW1 += (double)partials[7 * i + 5];
    SW2 += (double)partials[7 * i + 6];
  }
  for (int off = 32; off; off >>= 1) {
    C0 += __shfl_down(C0, off);
    C1 += __shfl_down(C1, off);
    C2 += __shfl_down(C2, off);
    SW += __shfl_down(SW, off);
    SW0 += __shfl_down(SW0, off);
    SW1 += __shfl_down(SW1, off);
    SW2 += __shfl_down(SW2, off);
  }
  __shared__ double red[7][NTHREADS / 64];
  const int lane = threadIdx.x & 63;
  const int wid = threadIdx.x >> 6;
  if (lane == 0) {
    red[0][wid] = C0;
    red[1][wid] = C1;
    red[2][wid] = C2;
    red[3][wid] = SW;
    red[4][wid] = SW0;
    red[5][wid] = SW1;
    red[6][wid] = SW2;
  }
  __syncthreads();
  if (threadIdx.x == 0) {
    double c0 = 0, c1 = 0, c2 = 0, s = 0, s0 = 0, s1 = 0, s2 = 0;
#pragma unroll
    for (int w = 0; w < NTHREADS / 64; ++w) {
      c0 += red[0][w];
      c1 += red[1][w];
      c2 += red[2][w];
      s += red[3][w];
      s0 += red[4][w];
      s1 += red[5][w];
      s2 += red[6][w];
    }
    const float v0 = basis[0], v1 = basis[1];
    float lev[4] = {-v0 - v1, -v0 + v1, v0 - v1, v0 + v1};
    float e0[4] = {-1.f, -1.f, 1.f, 1.f};
    float e1[4] = {-1.f, 1.f, -1.f, 1.f};
#define CSWAP(i, j)                                                   \
    if (lev[i] > lev[j]) {                                            \
      float t = lev[i]; lev[i] = lev[j]; lev[j] = t;                  \
      t = e0[i]; e0[i] = e0[j]; e0[j] = t;                            \
      t = e1[i]; e1[i] = e1[j]; e1[j] = t;                            \
    }
    CSWAP(0, 1) CSWAP(2, 3) CSWAP(0, 2) CSWAP(1, 3) CSWAP(1, 2)
#undef CSWAP
    const double A0 = e0[0], A1 = e0[1], A2 = e0[2], A3 = e0[3];
    const double B0 = e1[0], B1 = e1[1], B2 = e1[2], B3 = e1[3];
    const double N = (double)n;
    // telescoped sums over the monotone one-hot
    const double Sb0 = A0 * s + (A1 - A0) * s0 + (A2 - A1) * s1 + (A3 - A2) * s2;
    const double Sb1 = B0 * s + (B1 - B0) * s0 + (B2 - B1) * s1 + (B3 - B2) * s2;
    const double P0 = A0 * B0, P1 = A1 * B1, P2 = A2 * B2, P3 = A3 * B3;
    const double S01 = P0 * N + (P1 - P0) * c0 + (P2 - P1) * c1 + (P3 - P2) * c2;
    const double det = N * N - S01 * S01;
    const double nv0 = (N * Sb0 - S01 * Sb1) / det;
    const double nv1 = (N * Sb1 - S01 * Sb0) / det;
    out_basis[0] = (float)(0.9 * (double)v0 + 0.1 * nv0);
    out_basis[1] = (float)(0.9 * (double)v1 + 0.1 * nv1);
  }
}

extern "C" void kernel_launch(void* const* d_in, const int* in_sizes, int n_in,
                              void* d_out, int out_size, void* d_ws, size_t ws_size,
                              hipStream_t stream) {
  const float* x = (const float*)d_in[0];
  const float* basis = (const float*)d_in[1];
  float* out = (float*)d_out;
  const int n = in_sizes[0];
  float* partials = (float*)d_ws;  // nblocks * 7 floats

  int nblocks = NBLOCKS;
  const int maxb = (int)(ws_size / (7 * sizeof(float)));
  if (nblocks > maxb) nblocks = maxb;
  if (nblocks < 1) nblocks = 1;

  const int n4 = n / 4;
  lq_stats<<<nblocks, NTHREADS, 0, stream>>>(x, basis, partials, n4);
  lq_quant<<<NBLOCKS, NTHREADS, 0, stream>>>(x, basis, out, n, n4);
  lq_final<<<1, NTHREADS, 0, stream>>>(partials, basis, out + n, n, nblocks);
}